// Round 5
// baseline (453.065 us; speedup 1.0000x reference)
//
#include <hip/hip_runtime.h>

typedef unsigned short u16;
typedef __attribute__((ext_vector_type(8))) short bf16x8;
typedef __attribute__((ext_vector_type(4))) float f32x4;

#define B_SZ   2
#define L_SZ   2048
#define DM     1024
#define DI     2048
#define NST    16
#define RNK    64
#define TOK    (B_SZ * L_SZ)   // 4096
#define NC     32              // scan chunks
#define CLEN   (L_SZ / NC)     // 64 steps per chunk
#define XDS    128             // x_dbl row stride (padded from 96)
#define KSPL   8               // K-split for xdbl gemm

__device__ __forceinline__ float bf2f(u16 u) {
    return __uint_as_float(((unsigned int)u) << 16);
}
__device__ __forceinline__ u16 f2bf(float f) {
    unsigned int x = __float_as_uint(f);
    x += 0x7fffu + ((x >> 16) & 1u);   // RNE
    return (u16)(x >> 16);
}
__device__ __forceinline__ void bf2x2(unsigned int p, float& lo, float& hi) {
    lo = __uint_as_float(p << 16);
    hi = __uint_as_float(p & 0xffff0000u);
}
__device__ __forceinline__ float silu(float v) {
    return v / (1.f + __expf(-v));
}
__device__ __forceinline__ float softplus_f(float v) {
    return (v > 20.f) ? v : log1pf(__expf(v));
}

// ---------------------------------------------------------------------------
// f32 -> bf16 conversion (vectorized x4); n4 = elements/4
// ---------------------------------------------------------------------------
__global__ __launch_bounds__(256)
void cvt_f2b(const float* __restrict__ src, u16* __restrict__ dst, int n4)
{
    const int i = blockIdx.x * 256 + threadIdx.x;
    if (i < n4) {
        const float4 v = ((const float4*)src)[i];
        ushort4 o;
        o.x = f2bf(v.x); o.y = f2bf(v.y); o.z = f2bf(v.z); o.w = f2bf(v.w);
        ((ushort4*)dst)[i] = o;
    }
}

// W_x [96 x 2048] f32 -> [128 x 2048] bf16, rows 96..127 zeroed
__global__ __launch_bounds__(256)
void cvt_wx(const float* __restrict__ src, u16* __restrict__ dst)
{
    const int i = blockIdx.x * 256 + threadIdx.x;   // [0, 128*2048/4)
    const int row = (i * 4) >> 11;
    ushort4 o;
    if (row < 96) {
        const float4 v = ((const float4*)src)[i];
        o.x = f2bf(v.x); o.y = f2bf(v.y); o.z = f2bf(v.z); o.w = f2bf(v.w);
    } else {
        o.x = o.y = o.z = o.w = 0;
    }
    ((ushort4*)dst)[i] = o;
}

// ---------------------------------------------------------------------------
// GEMM  C[M][N] = A[M][K] @ B[N][K]^T   (both operands K-contiguous bf16)
// 128x128 tile, BK=32, 4 waves (2x2 of 64x64), mfma_f32_16x16x32_bf16.
// EPI==0: plain f32 store to outF (ld = N)   [final out_proj]
// EPI==1: in_proj epilogue: col<DI -> out0=x_m (bf16); col>=DI -> out1=silu (bf16)
// EPI==2: delta epilogue: outF = softplus(v + bias[gcol])
// ---------------------------------------------------------------------------
template<int EPI>
__global__ __launch_bounds__(256, 2)
void gemm_bt(const u16* __restrict__ A, const u16* __restrict__ B,
             const int K, const int N,
             u16* __restrict__ out0, u16* __restrict__ out1,
             float* __restrict__ outF, const float* __restrict__ bias)
{
    __shared__ u16 sA[128 * 40];
    __shared__ u16 sB[128 * 40];

    const int tid  = threadIdx.x;
    const int rowBase = blockIdx.x << 7;
    const int colBase = blockIdx.y << 7;
    const int wave = tid >> 6, lane = tid & 63;
    const int wm = (wave >> 1) << 6;
    const int wn = (wave & 1) << 6;
    const int lrow = lane & 15, quad = lane >> 4;

    const int sr  = tid >> 2;
    const int skc = tid & 3;
    const u16* Ap = A + (size_t)(rowBase + sr) * K + skc * 8;
    const u16* Bp = B + (size_t)(colBase + sr) * K + skc * 8;
    const size_t rowJump = (size_t)64 * K;
    const int sLds = sr * 40 + skc * 8;

    f32x4 acc[4][4];
#pragma unroll
    for (int i = 0; i < 4; ++i)
#pragma unroll
        for (int j = 0; j < 4; ++j) acc[i][j] = (f32x4){0.f, 0.f, 0.f, 0.f};

    uint4 pa0 = *(const uint4*)(Ap);
    uint4 pa1 = *(const uint4*)(Ap + rowJump);
    uint4 pb0 = *(const uint4*)(Bp);
    uint4 pb1 = *(const uint4*)(Bp + rowJump);

    const int KT = K >> 5;
    for (int kt = 0; kt < KT; ++kt) {
        *(uint4*)&sA[sLds]           = pa0;
        *(uint4*)&sA[sLds + 64 * 40] = pa1;
        *(uint4*)&sB[sLds]           = pb0;
        *(uint4*)&sB[sLds + 64 * 40] = pb1;
        __syncthreads();

        if (kt + 1 < KT) {
            const int ko = (kt + 1) * 32;
            pa0 = *(const uint4*)(Ap + ko);
            pa1 = *(const uint4*)(Ap + ko + rowJump);
            pb0 = *(const uint4*)(Bp + ko);
            pb1 = *(const uint4*)(Bp + ko + rowJump);
        }

        bf16x8 af[4], bfr[4];
#pragma unroll
        for (int i = 0; i < 4; ++i)
            af[i] = *(const bf16x8*)&sA[(wm + i * 16 + lrow) * 40 + quad * 8];
#pragma unroll
        for (int j = 0; j < 4; ++j)
            bfr[j] = *(const bf16x8*)&sB[(wn + j * 16 + lrow) * 40 + quad * 8];

#pragma unroll
        for (int i = 0; i < 4; ++i)
#pragma unroll
            for (int j = 0; j < 4; ++j)
                acc[i][j] = __builtin_amdgcn_mfma_f32_16x16x32_bf16(
                    af[i], bfr[j], acc[i][j], 0, 0, 0);
        __syncthreads();
    }

#pragma unroll
    for (int i = 0; i < 4; ++i) {
#pragma unroll
        for (int j = 0; j < 4; ++j) {
            const int gcol = colBase + wn + j * 16 + lrow;
            float bb = 0.f;
            if (EPI == 2) bb = bias[gcol];
#pragma unroll
            for (int r = 0; r < 4; ++r) {
                const int grow = rowBase + wm + i * 16 + quad * 4 + r;
                const float v = acc[i][j][r];
                if (EPI == 0) {
                    outF[(size_t)grow * N + gcol] = v;
                } else if (EPI == 2) {
                    outF[(size_t)grow * N + gcol] = softplus_f(v + bb);
                } else {
                    if (gcol < DI) out0[(size_t)grow * DI + gcol] = f2bf(v);
                    else           out1[(size_t)grow * DI + (gcol - DI)] = f2bf(silu(v));
                }
            }
        }
    }
}

// ---------------------------------------------------------------------------
// xdbl GEMM: part[ks][128 tokens][128] = xc_tile @ WxP^T over K-slice ks*256.
// grid (TOK/128, KSPL). Same tile structure as gemm_bt.
// ---------------------------------------------------------------------------
__global__ __launch_bounds__(256, 2)
void gemm_xdbl(const u16* __restrict__ A, const u16* __restrict__ B,
               float* __restrict__ part)
{
    __shared__ u16 sA[128 * 40];
    __shared__ u16 sB[128 * 40];

    const int tid  = threadIdx.x;
    const int rowBase = blockIdx.x << 7;
    const int ks   = blockIdx.y;
    const int k0   = ks * (DI / KSPL);
    const int wave = tid >> 6, lane = tid & 63;
    const int wm = (wave >> 1) << 6;
    const int wn = (wave & 1) << 6;
    const int lrow = lane & 15, quad = lane >> 4;

    const int sr  = tid >> 2;
    const int skc = tid & 3;
    const u16* Ap = A + (size_t)(rowBase + sr) * DI + k0 + skc * 8;
    const u16* Bp = B + (size_t)sr * DI + k0 + skc * 8;
    const size_t rowJump = (size_t)64 * DI;
    const int sLds = sr * 40 + skc * 8;

    f32x4 acc[4][4];
#pragma unroll
    for (int i = 0; i < 4; ++i)
#pragma unroll
        for (int j = 0; j < 4; ++j) acc[i][j] = (f32x4){0.f, 0.f, 0.f, 0.f};

    uint4 pa0 = *(const uint4*)(Ap);
    uint4 pa1 = *(const uint4*)(Ap + rowJump);
    uint4 pb0 = *(const uint4*)(Bp);
    uint4 pb1 = *(const uint4*)(Bp + rowJump);

    const int KT = (DI / KSPL) >> 5;            // 8
    for (int kt = 0; kt < KT; ++kt) {
        *(uint4*)&sA[sLds]           = pa0;
        *(uint4*)&sA[sLds + 64 * 40] = pa1;
        *(uint4*)&sB[sLds]           = pb0;
        *(uint4*)&sB[sLds + 64 * 40] = pb1;
        __syncthreads();

        if (kt + 1 < KT) {
            const int ko = (kt + 1) * 32;
            pa0 = *(const uint4*)(Ap + ko);
            pa1 = *(const uint4*)(Ap + ko + rowJump);
            pb0 = *(const uint4*)(Bp + ko);
            pb1 = *(const uint4*)(Bp + ko + rowJump);
        }

        bf16x8 af[4], bfr[4];
#pragma unroll
        for (int i = 0; i < 4; ++i)
            af[i] = *(const bf16x8*)&sA[(wm + i * 16 + lrow) * 40 + quad * 8];
#pragma unroll
        for (int j = 0; j < 4; ++j)
            bfr[j] = *(const bf16x8*)&sB[(wn + j * 16 + lrow) * 40 + quad * 8];

#pragma unroll
        for (int i = 0; i < 4; ++i)
#pragma unroll
            for (int j = 0; j < 4; ++j)
                acc[i][j] = __builtin_amdgcn_mfma_f32_16x16x32_bf16(
                    af[i], bfr[j], acc[i][j], 0, 0, 0);
        __syncthreads();
    }

    float* base = part + (size_t)ks * TOK * XDS;
#pragma unroll
    for (int i = 0; i < 4; ++i) {
#pragma unroll
        for (int j = 0; j < 4; ++j) {
            const int gcol = wn + j * 16 + lrow;
#pragma unroll
            for (int r = 0; r < 4; ++r) {
                const int grow = rowBase + wm + i * 16 + quad * 4 + r;
                base[(size_t)grow * XDS + gcol] = acc[i][j][r];
            }
        }
    }
}

// sum the 8 K-slice partials -> xdblP [TOK x 128] f32; also emit dltB
// (cols 0..63 as bf16, K-contiguous [TOK x 64]) for the delta MFMA GEMM.
__global__ __launch_bounds__(256)
void reduce_part(const float4* __restrict__ part, float4* __restrict__ xdbl,
                 u16* __restrict__ dltB)
{
    const int i = blockIdx.x * 256 + threadIdx.x;   // [0, TOK*XDS/4)
    const int n4 = TOK * XDS / 4;
    float4 s = part[i];
#pragma unroll
    for (int ks = 1; ks < KSPL; ++ks) {
        const float4 v = part[(size_t)ks * n4 + i];
        s.x += v.x; s.y += v.y; s.z += v.z; s.w += v.w;
    }
    xdbl[i] = s;
    const int col4 = (i & (XDS / 4 - 1)) * 4;
    if (col4 < RNK) {
        const int row = i >> 5;                      // XDS/4 = 32
        ushort4 o;
        o.x = f2bf(s.x); o.y = f2bf(s.y); o.z = f2bf(s.z); o.w = f2bf(s.w);
        *(ushort4*)(dltB + (size_t)row * RNK + col4) = o;
    }
}

// ---------------------------------------------------------------------------
// causal depthwise conv (K=4) + silu
// ---------------------------------------------------------------------------
__global__ __launch_bounds__(256)
void conv_silu_kernel(const u16* __restrict__ xm, const float* __restrict__ cw,
                      const float* __restrict__ cb, u16* __restrict__ xc)
{
    const int idx = blockIdx.x * 256 + threadIdx.x;
    const int ch = idx & (DI - 1);
    const int t  = idx >> 11;
    const int l  = t & (L_SZ - 1);

    const float4 wv = *(const float4*)(cw + ch * 4);

    float acc = cb[ch];
    if (l >= 3) acc += wv.x * bf2f(xm[(size_t)(t - 3) * DI + ch]);
    if (l >= 2) acc += wv.y * bf2f(xm[(size_t)(t - 2) * DI + ch]);
    if (l >= 1) acc += wv.z * bf2f(xm[(size_t)(t - 1) * DI + ch]);
    acc += wv.w * bf2f(xm[(size_t)t * DI + ch]);

    xc[idx] = f2bf(silu(acc));
}

// ---------------------------------------------------------------------------
// Chunked selective scan. thread = channel; 16 states in registers.
// ---------------------------------------------------------------------------
__global__ __launch_bounds__(256)
void scan_pass1(const float* __restrict__ delta, const float* __restrict__ xdbl,
                const u16* __restrict__ xc, const float* __restrict__ A_log,
                float* __restrict__ hfin, float* __restrict__ aprod)
{
    const int tid = threadIdx.x;
    const int ch  = blockIdx.x * 256 + tid;
    const int b   = blockIdx.y / NC;
    const int c   = blockIdx.y % NC;
    const int t0  = b * L_SZ + c * CLEN;

    __shared__ float sB[CLEN][16];
    for (int idx = tid; idx < CLEN * 16; idx += 256) {
        const int i = idx >> 4, nn = idx & 15;
        sB[i][nn] = xdbl[(size_t)(t0 + i) * XDS + 64 + nn];
    }

    float A[16];
    {
        const float4* Ar = (const float4*)(A_log + (size_t)ch * 16);
#pragma unroll
        for (int k = 0; k < 4; ++k) {
            const float4 v = Ar[k];
            A[4*k+0] = -__expf(v.x); A[4*k+1] = -__expf(v.y);
            A[4*k+2] = -__expf(v.z); A[4*k+3] = -__expf(v.w);
        }
    }
    __syncthreads();

    float h[16], P[16];
#pragma unroll
    for (int n = 0; n < 16; ++n) { h[n] = 0.f; P[n] = 1.f; }

    for (int i = 0; i < CLEN; ++i) {
        const size_t tok = (size_t)(t0 + i);
        const float d  = delta[tok * DI + ch];
        const float xv = bf2f(xc[tok * DI + ch]);
        const float dx = d * xv;
#pragma unroll
        for (int k = 0; k < 4; ++k) {
            const float4 Bv = *(const float4*)&sB[i][k * 4];
#pragma unroll
            for (int j = 0; j < 4; ++j) {
                const int n = k * 4 + j;
                const float e = __expf(d * A[n]);
                h[n] = e * h[n] + dx * (&Bv.x)[j];
                P[n] *= e;
            }
        }
    }

    float* hp = hfin  + ((size_t)(b * NC + c) * DI + ch) * 16;
    float* pp = aprod + ((size_t)(b * NC + c) * DI + ch) * 16;
#pragma unroll
    for (int k = 0; k < 4; ++k) {
        *(float4*)(hp + 4 * k) = (float4){h[4*k], h[4*k+1], h[4*k+2], h[4*k+3]};
        *(float4*)(pp + 4 * k) = (float4){P[4*k], P[4*k+1], P[4*k+2], P[4*k+3]};
    }
}

__global__ __launch_bounds__(256)
void scan_combine(const float* __restrict__ hfin, const float* __restrict__ aprod,
                  float* __restrict__ h0buf)
{
    const int idx  = blockIdx.x * 256 + threadIdx.x;
    const int b    = idx >> 15;
    const int base = idx & 32767;
    float h0 = 0.f;
    for (int c = 0; c < NC; ++c) {
        const size_t o = (size_t)(b * NC + c) * 32768 + base;
        h0buf[o] = h0;
        h0 = hfin[o] + aprod[o] * h0;
    }
}

__global__ __launch_bounds__(256)
void scan_pass2(const float* __restrict__ delta, const float* __restrict__ xdbl,
                const u16* __restrict__ xc, const u16* __restrict__ sres,
                const float* __restrict__ A_log, const float* __restrict__ Dp,
                const float* __restrict__ h0buf, u16* __restrict__ yfin)
{
    const int tid = threadIdx.x;
    const int ch  = blockIdx.x * 256 + tid;
    const int b   = blockIdx.y / NC;
    const int c   = blockIdx.y % NC;
    const int t0  = b * L_SZ + c * CLEN;

    __shared__ float sB[CLEN][16], sC[CLEN][16];
    for (int idx = tid; idx < CLEN * 16; idx += 256) {
        const int i = idx >> 4, nn = idx & 15;
        sB[i][nn] = xdbl[(size_t)(t0 + i) * XDS + 64 + nn];
        sC[i][nn] = xdbl[(size_t)(t0 + i) * XDS + 80 + nn];
    }

    float A[16];
    {
        const float4* Ar = (const float4*)(A_log + (size_t)ch * 16);
#pragma unroll
        for (int k = 0; k < 4; ++k) {
            const float4 v = Ar[k];
            A[4*k+0] = -__expf(v.x); A[4*k+1] = -__expf(v.y);
            A[4*k+2] = -__expf(v.z); A[4*k+3] = -__expf(v.w);
        }
    }
    const float Dval = Dp[ch];

    float h[16];
    {
        const float4* hp = (const float4*)(h0buf + (size_t)(b * NC + c) * 32768 + (size_t)ch * 16);
#pragma unroll
        for (int k = 0; k < 4; ++k) {
            const float4 v = hp[k];
            h[4*k+0] = v.x; h[4*k+1] = v.y; h[4*k+2] = v.z; h[4*k+3] = v.w;
        }
    }
    __syncthreads();

    for (int i = 0; i < CLEN; ++i) {
        const size_t tok = (size_t)(t0 + i);
        const float d  = delta[tok * DI + ch];
        const float xv = bf2f(xc[tok * DI + ch]);
        const float rv = bf2f(sres[tok * DI + ch]);
        const float dx = d * xv;
        float acc0 = 0.f, acc1 = 0.f, acc2 = 0.f, acc3 = 0.f;
#pragma unroll
        for (int k = 0; k < 4; ++k) {
            const float4 Bv = *(const float4*)&sB[i][k * 4];
            const float4 Cv = *(const float4*)&sC[i][k * 4];
#pragma unroll
            for (int j = 0; j < 4; ++j) {
                const int n = k * 4 + j;
                const float e = __expf(d * A[n]);
                h[n] = e * h[n] + dx * (&Bv.x)[j];
                const float t = h[n] * (&Cv.x)[j];
                if (j == 0) acc0 += t; else if (j == 1) acc1 += t;
                else if (j == 2) acc2 += t; else acc3 += t;
            }
        }
        const float p = (acc0 + acc1) + (acc2 + acc3);
        const float y = (p + Dval * xv) * rv;
        yfin[tok * DI + ch] = f2bf(y);
    }
}

// ---------------------------------------------------------------------------
extern "C" void kernel_launch(void* const* d_in, const int* in_sizes, int n_in,
                              void* d_out, int out_size, void* d_ws, size_t ws_size,
                              hipStream_t stream)
{
    const float* x      = (const float*)d_in[0];
    const float* W_in   = (const float*)d_in[1];
    const float* conv_w = (const float*)d_in[2];
    const float* conv_b = (const float*)d_in[3];
    const float* W_x    = (const float*)d_in[4];
    const float* W_dt   = (const float*)d_in[5];
    const float* b_dt   = (const float*)d_in[6];
    const float* A_log  = (const float*)d_in[7];
    const float* D_par  = (const float*)d_in[8];
    const float* W_out  = (const float*)d_in[9];
    float* out = (float*)d_out;

    char* ws = (char*)d_ws;
    size_t off = 0;
    u16* xb    = (u16*)(ws + off); off += (size_t)TOK * DM * 2;        //  8.4 MB
    u16* Winb  = (u16*)(ws + off); off += (size_t)(2 * DI) * DM * 2;   //  8.4 MB
    u16* Woutb = (u16*)(ws + off); off += (size_t)DM * DI * 2;         //  4.2 MB
    u16* Wxb   = (u16*)(ws + off); off += (size_t)XDS * DI * 2;        //  0.5 MB (padded)
    u16* Wdtb  = (u16*)(ws + off); off += (size_t)DI * RNK * 2;        //  0.3 MB
    u16* dltB  = (u16*)(ws + off); off += (size_t)TOK * RNK * 2;       //  0.5 MB
    u16* xm    = (u16*)(ws + off); off += (size_t)TOK * DI * 2;        // 16.8 MB
    u16* xc    = (u16*)(ws + off); off += (size_t)TOK * DI * 2;        // 16.8 MB
    u16* sres  = (u16*)(ws + off); off += (size_t)TOK * DI * 2;        // 16.8 MB
    float* xdblP = (float*)(ws + off); off += (size_t)TOK * XDS * 4;   //  2.1 MB
    float* delta = (float*)(ws + off); off += (size_t)TOK * DI * 4;    // 33.6 MB
    float* hfin  = (float*)(ws + off); off += (size_t)NC * B_SZ * DI * NST * 4; // 8.4 MB
    float* aprod = (float*)(ws + off); off += (size_t)NC * B_SZ * DI * NST * 4; // 8.4 MB
    float* h0buf = (float*)(ws + off); off += (size_t)NC * B_SZ * DI * NST * 4; // 8.4 MB
    u16* yfin = xm;              // xm dead after conv — reuse
    float* part = hfin;          // hfin+aprod dead until scan_pass1 — reuse for K-split partials

    // 0. convert GEMM operands f32 -> bf16
    cvt_f2b<<<(TOK * DM / 4 + 255) / 256, 256, 0, stream>>>(x, xb, TOK * DM / 4);
    cvt_f2b<<<(2 * DI * DM / 4 + 255) / 256, 256, 0, stream>>>(W_in, Winb, 2 * DI * DM / 4);
    cvt_f2b<<<(DM * DI / 4 + 255) / 256, 256, 0, stream>>>(W_out, Woutb, DM * DI / 4);
    cvt_wx<<<(XDS * DI / 4) / 256, 256, 0, stream>>>(W_x, Wxb);
    cvt_f2b<<<(DI * RNK / 4 + 255) / 256, 256, 0, stream>>>(W_dt, Wdtb, DI * RNK / 4);

    // 1. in_proj
    gemm_bt<1><<<dim3(TOK / 128, (2 * DI) / 128), 256, 0, stream>>>(
        xb, Winb, DM, 2 * DI, xm, sres, nullptr, nullptr);

    // 2. causal depthwise conv + silu
    conv_silu_kernel<<<(TOK * DI) / 256, 256, 0, stream>>>(xm, conv_w, conv_b, xc);

    // 3. x_dbl = xc @ W_x^T  (MFMA, K-split 8, then reduce + emit dltB bf16)
    gemm_xdbl<<<dim3(TOK / 128, KSPL), 256, 0, stream>>>(xc, Wxb, part);
    reduce_part<<<(TOK * XDS / 4) / 256, 256, 0, stream>>>(
        (const float4*)part, (float4*)xdblP, dltB);

    // 4. delta = softplus(dltB @ W_dt^T + b_dt)  — MFMA, K=64
    gemm_bt<2><<<dim3(TOK / 128, DI / 128), 256, 0, stream>>>(
        dltB, Wdtb, RNK, DI, nullptr, nullptr, delta, b_dt);

    // 5. chunked selective scan
    scan_pass1<<<dim3(DI / 256, B_SZ * NC), 256, 0, stream>>>(
        delta, xdblP, xc, A_log, hfin, aprod);
    scan_combine<<<(B_SZ * DI * NST) / 256, 256, 0, stream>>>(hfin, aprod, h0buf);
    scan_pass2<<<dim3(DI / 256, B_SZ * NC), 256, 0, stream>>>(
        delta, xdblP, xc, sres, A_log, D_par, h0buf, yfin);

    // 6. out = yfin @ W_out^T (f32 store)
    gemm_bt<0><<<dim3(TOK / 128, DM / 128), 256, 0, stream>>>(
        yfin, Woutb, DI, DM, nullptr, nullptr, out, nullptr);
}

// Round 6
// 374.892 us; speedup vs baseline: 1.2085x; 1.2085x over previous
//
#include <hip/hip_runtime.h>

typedef unsigned short u16;
typedef __attribute__((ext_vector_type(8))) short bf16x8;
typedef __attribute__((ext_vector_type(4))) float f32x4;

#define B_SZ   2
#define L_SZ   2048
#define DM     1024
#define DI     2048
#define NST    16
#define RNK    64
#define TOK    (B_SZ * L_SZ)   // 4096
#define NC     32              // scan chunks
#define CLEN   (L_SZ / NC)     // 64 steps per chunk
#define XDS    128             // x_dbl row stride (padded from 96)
#define KSPL   8               // K-split for xdbl gemm

__device__ __forceinline__ float bf2f(u16 u) {
    return __uint_as_float(((unsigned int)u) << 16);
}
__device__ __forceinline__ u16 f2bf(float f) {
    unsigned int x = __float_as_uint(f);
    x += 0x7fffu + ((x >> 16) & 1u);   // RNE
    return (u16)(x >> 16);
}
__device__ __forceinline__ void bf2x2(unsigned int p, float& lo, float& hi) {
    lo = __uint_as_float(p << 16);
    hi = __uint_as_float(p & 0xffff0000u);
}
__device__ __forceinline__ float silu(float v) {
    return v / (1.f + __expf(-v));
}
__device__ __forceinline__ float softplus_f(float v) {
    return (v > 20.f) ? v : log1pf(__expf(v));
}
// 16-byte async global->LDS (gfx950). LDS dest = wave-uniform base + lane*16;
// our mapping (thread tid stages LDS bytes tid*16..) satisfies that.
__device__ __forceinline__ void gload16(const u16* g, u16* l) {
    __builtin_amdgcn_global_load_lds(
        (const __attribute__((address_space(1))) void*)g,
        (__attribute__((address_space(3))) void*)l, 16, 0, 0);
}

// ---------------------------------------------------------------------------
// f32 -> bf16 conversion (vectorized x4); n4 = elements/4
// ---------------------------------------------------------------------------
__global__ __launch_bounds__(256)
void cvt_f2b(const float* __restrict__ src, u16* __restrict__ dst, int n4)
{
    const int i = blockIdx.x * 256 + threadIdx.x;
    if (i < n4) {
        const float4 v = ((const float4*)src)[i];
        ushort4 o;
        o.x = f2bf(v.x); o.y = f2bf(v.y); o.z = f2bf(v.z); o.w = f2bf(v.w);
        ((ushort4*)dst)[i] = o;
    }
}

// W_x [96 x 2048] f32 -> [128 x 2048] bf16, rows 96..127 zeroed
__global__ __launch_bounds__(256)
void cvt_wx(const float* __restrict__ src, u16* __restrict__ dst)
{
    const int i = blockIdx.x * 256 + threadIdx.x;   // [0, 128*2048/4)
    const int row = (i * 4) >> 11;
    ushort4 o;
    if (row < 96) {
        const float4 v = ((const float4*)src)[i];
        o.x = f2bf(v.x); o.y = f2bf(v.y); o.z = f2bf(v.z); o.w = f2bf(v.w);
    } else {
        o.x = o.y = o.z = o.w = 0;
    }
    ((ushort4*)dst)[i] = o;
}

// ---------------------------------------------------------------------------
// GEMM  C[M][N] = A[M][K] @ B[N][K]^T   (both operands K-contiguous bf16)
// 128x128 tile, BK=32, 4 waves (2x2 of 64x64), mfma_f32_16x16x32_bf16.
// m97-style staging: global_load_lds width=16, unpadded LDS [128][32].
// MFMA operands SWAPPED (acc = B-frag x A-frag) so each thread's 4 acc
// values are 4 consecutive CHANNELS -> packed ushort4/float4 stores.
//   thread (i,j): token = rowBase+wm+i*16+(lane&15), ch = colBase+wn+j*16+quad*4
// EPI==0: float4 store to outF (ld = N)   [final out_proj]
// EPI==1: in_proj: ch<DI -> out0=x_m (bf16x4); ch>=DI -> out1=silu (bf16x4)
// EPI==2: delta: outF = softplus(v + bias[ch]) float4
// ---------------------------------------------------------------------------
template<int EPI>
__global__ __launch_bounds__(256, 2)
void gemm_bt(const u16* __restrict__ A, const u16* __restrict__ B,
             const int K, const int N,
             u16* __restrict__ out0, u16* __restrict__ out1,
             float* __restrict__ outF, const float* __restrict__ bias)
{
    __shared__ u16 sA[128 * 32];
    __shared__ u16 sB[128 * 32];

    const int tid  = threadIdx.x;
    const int rowBase = blockIdx.x << 7;
    const int colBase = blockIdx.y << 7;
    const int wave = tid >> 6, lane = tid & 63;
    const int wm = (wave >> 1) << 6;
    const int wn = (wave & 1) << 6;
    const int lrow = lane & 15, quad = lane >> 4;

    // staging: thread tid -> LDS bytes [tid*16, tid*16+16) ; row=tid>>2, kchunk=tid&3
    const int sr  = tid >> 2;
    const int skc = tid & 3;
    const u16* Ap = A + (size_t)(rowBase + sr) * K + skc * 8;
    const u16* Bp = B + (size_t)(colBase + sr) * K + skc * 8;
    const size_t rowJump = (size_t)64 * K;
    u16* lA0 = &sA[tid * 8];
    u16* lA1 = &sA[64 * 32 + tid * 8];
    u16* lB0 = &sB[tid * 8];
    u16* lB1 = &sB[64 * 32 + tid * 8];

    f32x4 acc[4][4];
#pragma unroll
    for (int i = 0; i < 4; ++i)
#pragma unroll
        for (int j = 0; j < 4; ++j) acc[i][j] = (f32x4){0.f, 0.f, 0.f, 0.f};

    const int KT = K >> 5;
    for (int kt = 0; kt < KT; ++kt) {
        const int ko = kt * 32;
        gload16(Ap + ko, lA0);
        gload16(Ap + ko + rowJump, lA1);
        gload16(Bp + ko, lB0);
        gload16(Bp + ko + rowJump, lB1);
        __syncthreads();                      // drains vmcnt -> LDS ready

        bf16x8 af[4], bfr[4];
#pragma unroll
        for (int i = 0; i < 4; ++i)
            af[i] = *(const bf16x8*)&sA[(wm + i * 16 + lrow) * 32 + quad * 8];
#pragma unroll
        for (int j = 0; j < 4; ++j)
            bfr[j] = *(const bf16x8*)&sB[(wn + j * 16 + lrow) * 32 + quad * 8];

#pragma unroll
        for (int i = 0; i < 4; ++i)
#pragma unroll
            for (int j = 0; j < 4; ++j)
                acc[i][j] = __builtin_amdgcn_mfma_f32_16x16x32_bf16(
                    bfr[j], af[i], acc[i][j], 0, 0, 0);   // swapped: C^T frags
        __syncthreads();                      // protect LDS from next kt
    }

    // epilogue: thread holds 4 consecutive channels per (i,j)
#pragma unroll
    for (int i = 0; i < 4; ++i) {
        const int token = rowBase + wm + i * 16 + lrow;
#pragma unroll
        for (int j = 0; j < 4; ++j) {
            const int ch = colBase + wn + j * 16 + quad * 4;
            const f32x4 v = acc[i][j];
            if (EPI == 0) {
                *(float4*)&outF[(size_t)token * N + ch] =
                    (float4){v[0], v[1], v[2], v[3]};
            } else if (EPI == 2) {
                const float4 bb = *(const float4*)&bias[ch];
                *(float4*)&outF[(size_t)token * N + ch] =
                    (float4){softplus_f(v[0] + bb.x), softplus_f(v[1] + bb.y),
                             softplus_f(v[2] + bb.z), softplus_f(v[3] + bb.w)};
            } else {
                if (ch < DI) {
                    ushort4 o;
                    o.x = f2bf(v[0]); o.y = f2bf(v[1]);
                    o.z = f2bf(v[2]); o.w = f2bf(v[3]);
                    *(ushort4*)&out0[(size_t)token * DI + ch] = o;
                } else {
                    ushort4 o;
                    o.x = f2bf(silu(v[0])); o.y = f2bf(silu(v[1]));
                    o.z = f2bf(silu(v[2])); o.w = f2bf(silu(v[3]));
                    *(ushort4*)&out1[(size_t)token * DI + (ch - DI)] = o;
                }
            }
        }
    }
}

// ---------------------------------------------------------------------------
// xdbl GEMM: part[ks][128 tokens][128] = xc_tile @ WxP^T over K-slice ks*256.
// grid (TOK/128, KSPL). Same structure as gemm_bt (swapped MFMA, gload16).
// ---------------------------------------------------------------------------
__global__ __launch_bounds__(256, 2)
void gemm_xdbl(const u16* __restrict__ A, const u16* __restrict__ B,
               float* __restrict__ part)
{
    __shared__ u16 sA[128 * 32];
    __shared__ u16 sB[128 * 32];

    const int tid  = threadIdx.x;
    const int rowBase = blockIdx.x << 7;
    const int ks   = blockIdx.y;
    const int k0   = ks * (DI / KSPL);
    const int wave = tid >> 6, lane = tid & 63;
    const int wm = (wave >> 1) << 6;
    const int wn = (wave & 1) << 6;
    const int lrow = lane & 15, quad = lane >> 4;

    const int sr  = tid >> 2;
    const int skc = tid & 3;
    const u16* Ap = A + (size_t)(rowBase + sr) * DI + k0 + skc * 8;
    const u16* Bp = B + (size_t)sr * DI + k0 + skc * 8;
    const size_t rowJump = (size_t)64 * DI;
    u16* lA0 = &sA[tid * 8];
    u16* lA1 = &sA[64 * 32 + tid * 8];
    u16* lB0 = &sB[tid * 8];
    u16* lB1 = &sB[64 * 32 + tid * 8];

    f32x4 acc[4][4];
#pragma unroll
    for (int i = 0; i < 4; ++i)
#pragma unroll
        for (int j = 0; j < 4; ++j) acc[i][j] = (f32x4){0.f, 0.f, 0.f, 0.f};

    const int KT = (DI / KSPL) >> 5;            // 8
    for (int kt = 0; kt < KT; ++kt) {
        const int ko = kt * 32;
        gload16(Ap + ko, lA0);
        gload16(Ap + ko + rowJump, lA1);
        gload16(Bp + ko, lB0);
        gload16(Bp + ko + rowJump, lB1);
        __syncthreads();

        bf16x8 af[4], bfr[4];
#pragma unroll
        for (int i = 0; i < 4; ++i)
            af[i] = *(const bf16x8*)&sA[(wm + i * 16 + lrow) * 32 + quad * 8];
#pragma unroll
        for (int j = 0; j < 4; ++j)
            bfr[j] = *(const bf16x8*)&sB[(wn + j * 16 + lrow) * 32 + quad * 8];

#pragma unroll
        for (int i = 0; i < 4; ++i)
#pragma unroll
            for (int j = 0; j < 4; ++j)
                acc[i][j] = __builtin_amdgcn_mfma_f32_16x16x32_bf16(
                    bfr[j], af[i], acc[i][j], 0, 0, 0);
        __syncthreads();
    }

    float* base = part + (size_t)ks * TOK * XDS;
#pragma unroll
    for (int i = 0; i < 4; ++i) {
        const int token = rowBase + wm + i * 16 + lrow;
#pragma unroll
        for (int j = 0; j < 4; ++j) {
            const int ch = wn + j * 16 + quad * 4;
            const f32x4 v = acc[i][j];
            *(float4*)&base[(size_t)token * XDS + ch] =
                (float4){v[0], v[1], v[2], v[3]};
        }
    }
}

// sum the 8 K-slice partials -> xdblP [TOK x 128] f32; also emit dltB
// (cols 0..63 as bf16, K-contiguous [TOK x 64]) for the delta MFMA GEMM.
__global__ __launch_bounds__(256)
void reduce_part(const float4* __restrict__ part, float4* __restrict__ xdbl,
                 u16* __restrict__ dltB)
{
    const int i = blockIdx.x * 256 + threadIdx.x;   // [0, TOK*XDS/4)
    const int n4 = TOK * XDS / 4;
    float4 s = part[i];
#pragma unroll
    for (int ks = 1; ks < KSPL; ++ks) {
        const float4 v = part[(size_t)ks * n4 + i];
        s.x += v.x; s.y += v.y; s.z += v.z; s.w += v.w;
    }
    xdbl[i] = s;
    const int col4 = (i & (XDS / 4 - 1)) * 4;
    if (col4 < RNK) {
        const int row = i >> 5;                      // XDS/4 = 32
        ushort4 o;
        o.x = f2bf(s.x); o.y = f2bf(s.y); o.z = f2bf(s.z); o.w = f2bf(s.w);
        *(ushort4*)(dltB + (size_t)row * RNK + col4) = o;
    }
}

// ---------------------------------------------------------------------------
// causal depthwise conv (K=4) + silu
// ---------------------------------------------------------------------------
__global__ __launch_bounds__(256)
void conv_silu_kernel(const u16* __restrict__ xm, const float* __restrict__ cw,
                      const float* __restrict__ cb, u16* __restrict__ xc)
{
    const int idx = blockIdx.x * 256 + threadIdx.x;
    const int ch = idx & (DI - 1);
    const int t  = idx >> 11;
    const int l  = t & (L_SZ - 1);

    const float4 wv = *(const float4*)(cw + ch * 4);

    float acc = cb[ch];
    if (l >= 3) acc += wv.x * bf2f(xm[(size_t)(t - 3) * DI + ch]);
    if (l >= 2) acc += wv.y * bf2f(xm[(size_t)(t - 2) * DI + ch]);
    if (l >= 1) acc += wv.z * bf2f(xm[(size_t)(t - 1) * DI + ch]);
    acc += wv.w * bf2f(xm[(size_t)t * DI + ch]);

    xc[idx] = f2bf(silu(acc));
}

// ---------------------------------------------------------------------------
// Chunked selective scan. thread = channel; 16 states in registers.
// ---------------------------------------------------------------------------
__global__ __launch_bounds__(256)
void scan_pass1(const float* __restrict__ delta, const float* __restrict__ xdbl,
                const u16* __restrict__ xc, const float* __restrict__ A_log,
                float* __restrict__ hfin, float* __restrict__ aprod)
{
    const int tid = threadIdx.x;
    const int ch  = blockIdx.x * 256 + tid;
    const int b   = blockIdx.y / NC;
    const int c   = blockIdx.y % NC;
    const int t0  = b * L_SZ + c * CLEN;

    __shared__ float sB[CLEN][16];
    for (int idx = tid; idx < CLEN * 16; idx += 256) {
        const int i = idx >> 4, nn = idx & 15;
        sB[i][nn] = xdbl[(size_t)(t0 + i) * XDS + 64 + nn];
    }

    float A[16];
    {
        const float4* Ar = (const float4*)(A_log + (size_t)ch * 16);
#pragma unroll
        for (int k = 0; k < 4; ++k) {
            const float4 v = Ar[k];
            A[4*k+0] = -__expf(v.x); A[4*k+1] = -__expf(v.y);
            A[4*k+2] = -__expf(v.z); A[4*k+3] = -__expf(v.w);
        }
    }
    __syncthreads();

    float h[16], P[16];
#pragma unroll
    for (int n = 0; n < 16; ++n) { h[n] = 0.f; P[n] = 1.f; }

    for (int i = 0; i < CLEN; ++i) {
        const size_t tok = (size_t)(t0 + i);
        const float d  = delta[tok * DI + ch];
        const float xv = bf2f(xc[tok * DI + ch]);
        const float dx = d * xv;
#pragma unroll
        for (int k = 0; k < 4; ++k) {
            const float4 Bv = *(const float4*)&sB[i][k * 4];
#pragma unroll
            for (int j = 0; j < 4; ++j) {
                const int n = k * 4 + j;
                const float e = __expf(d * A[n]);
                h[n] = e * h[n] + dx * (&Bv.x)[j];
                P[n] *= e;
            }
        }
    }

    float* hp = hfin  + ((size_t)(b * NC + c) * DI + ch) * 16;
    float* pp = aprod + ((size_t)(b * NC + c) * DI + ch) * 16;
#pragma unroll
    for (int k = 0; k < 4; ++k) {
        *(float4*)(hp + 4 * k) = (float4){h[4*k], h[4*k+1], h[4*k+2], h[4*k+3]};
        *(float4*)(pp + 4 * k) = (float4){P[4*k], P[4*k+1], P[4*k+2], P[4*k+3]};
    }
}

__global__ __launch_bounds__(256)
void scan_combine(const float* __restrict__ hfin, const float* __restrict__ aprod,
                  float* __restrict__ h0buf)
{
    const int idx  = blockIdx.x * 256 + threadIdx.x;
    const int b    = idx >> 15;
    const int base = idx & 32767;
    float h0 = 0.f;
    for (int c = 0; c < NC; ++c) {
        const size_t o = (size_t)(b * NC + c) * 32768 + base;
        h0buf[o] = h0;
        h0 = hfin[o] + aprod[o] * h0;
    }
}

__global__ __launch_bounds__(256)
void scan_pass2(const float* __restrict__ delta, const float* __restrict__ xdbl,
                const u16* __restrict__ xc, const u16* __restrict__ sres,
                const float* __restrict__ A_log, const float* __restrict__ Dp,
                const float* __restrict__ h0buf, u16* __restrict__ yfin)
{
    const int tid = threadIdx.x;
    const int ch  = blockIdx.x * 256 + tid;
    const int b   = blockIdx.y / NC;
    const int c   = blockIdx.y % NC;
    const int t0  = b * L_SZ + c * CLEN;

    __shared__ float sB[CLEN][16], sC[CLEN][16];
    for (int idx = tid; idx < CLEN * 16; idx += 256) {
        const int i = idx >> 4, nn = idx & 15;
        sB[i][nn] = xdbl[(size_t)(t0 + i) * XDS + 64 + nn];
        sC[i][nn] = xdbl[(size_t)(t0 + i) * XDS + 80 + nn];
    }

    float A[16];
    {
        const float4* Ar = (const float4*)(A_log + (size_t)ch * 16);
#pragma unroll
        for (int k = 0; k < 4; ++k) {
            const float4 v = Ar[k];
            A[4*k+0] = -__expf(v.x); A[4*k+1] = -__expf(v.y);
            A[4*k+2] = -__expf(v.z); A[4*k+3] = -__expf(v.w);
        }
    }
    const float Dval = Dp[ch];

    float h[16];
    {
        const float4* hp = (const float4*)(h0buf + (size_t)(b * NC + c) * 32768 + (size_t)ch * 16);
#pragma unroll
        for (int k = 0; k < 4; ++k) {
            const float4 v = hp[k];
            h[4*k+0] = v.x; h[4*k+1] = v.y; h[4*k+2] = v.z; h[4*k+3] = v.w;
        }
    }
    __syncthreads();

    for (int i = 0; i < CLEN; ++i) {
        const size_t tok = (size_t)(t0 + i);
        const float d  = delta[tok * DI + ch];
        const float xv = bf2f(xc[tok * DI + ch]);
        const float rv = bf2f(sres[tok * DI + ch]);
        const float dx = d * xv;
        float acc0 = 0.f, acc1 = 0.f, acc2 = 0.f, acc3 = 0.f;
#pragma unroll
        for (int k = 0; k < 4; ++k) {
            const float4 Bv = *(const float4*)&sB[i][k * 4];
            const float4 Cv = *(const float4*)&sC[i][k * 4];
#pragma unroll
            for (int j = 0; j < 4; ++j) {
                const int n = k * 4 + j;
                const float e = __expf(d * A[n]);
                h[n] = e * h[n] + dx * (&Bv.x)[j];
                const float t = h[n] * (&Cv.x)[j];
                if (j == 0) acc0 += t; else if (j == 1) acc1 += t;
                else if (j == 2) acc2 += t; else acc3 += t;
            }
        }
        const float p = (acc0 + acc1) + (acc2 + acc3);
        const float y = (p + Dval * xv) * rv;
        yfin[tok * DI + ch] = f2bf(y);
    }
}

// ---------------------------------------------------------------------------
extern "C" void kernel_launch(void* const* d_in, const int* in_sizes, int n_in,
                              void* d_out, int out_size, void* d_ws, size_t ws_size,
                              hipStream_t stream)
{
    const float* x      = (const float*)d_in[0];
    const float* W_in   = (const float*)d_in[1];
    const float* conv_w = (const float*)d_in[2];
    const float* conv_b = (const float*)d_in[3];
    const float* W_x    = (const float*)d_in[4];
    const float* W_dt   = (const float*)d_in[5];
    const float* b_dt   = (const float*)d_in[6];
    const float* A_log  = (const float*)d_in[7];
    const float* D_par  = (const float*)d_in[8];
    const float* W_out  = (const float*)d_in[9];
    float* out = (float*)d_out;

    char* ws = (char*)d_ws;
    size_t off = 0;
    u16* xb    = (u16*)(ws + off); off += (size_t)TOK * DM * 2;        //  8.4 MB
    u16* Winb  = (u16*)(ws + off); off += (size_t)(2 * DI) * DM * 2;   //  8.4 MB
    u16* Woutb = (u16*)(ws + off); off += (size_t)DM * DI * 2;         //  4.2 MB
    u16* Wxb   = (u16*)(ws + off); off += (size_t)XDS * DI * 2;        //  0.5 MB (padded)
    u16* Wdtb  = (u16*)(ws + off); off += (size_t)DI * RNK * 2;        //  0.3 MB
    u16* dltB  = (u16*)(ws + off); off += (size_t)TOK * RNK * 2;       //  0.5 MB
    u16* xm    = (u16*)(ws + off); off += (size_t)TOK * DI * 2;        // 16.8 MB
    u16* xc    = (u16*)(ws + off); off += (size_t)TOK * DI * 2;        // 16.8 MB
    u16* sres  = (u16*)(ws + off); off += (size_t)TOK * DI * 2;        // 16.8 MB
    float* xdblP = (float*)(ws + off); off += (size_t)TOK * XDS * 4;   //  2.1 MB
    float* delta = (float*)(ws + off); off += (size_t)TOK * DI * 4;    // 33.6 MB
    float* hfin  = (float*)(ws + off); off += (size_t)NC * B_SZ * DI * NST * 4; // 8.4 MB
    float* aprod = (float*)(ws + off); off += (size_t)NC * B_SZ * DI * NST * 4; // 8.4 MB
    float* h0buf = (float*)(ws + off); off += (size_t)NC * B_SZ * DI * NST * 4; // 8.4 MB
    u16* yfin = xm;              // xm dead after conv — reuse
    float* part = hfin;          // hfin+aprod dead until scan_pass1 — reuse for K-split partials

    // 0. convert GEMM operands f32 -> bf16
    cvt_f2b<<<(TOK * DM / 4 + 255) / 256, 256, 0, stream>>>(x, xb, TOK * DM / 4);
    cvt_f2b<<<(2 * DI * DM / 4 + 255) / 256, 256, 0, stream>>>(W_in, Winb, 2 * DI * DM / 4);
    cvt_f2b<<<(DM * DI / 4 + 255) / 256, 256, 0, stream>>>(W_out, Woutb, DM * DI / 4);
    cvt_wx<<<(XDS * DI / 4) / 256, 256, 0, stream>>>(W_x, Wxb);
    cvt_f2b<<<(DI * RNK / 4 + 255) / 256, 256, 0, stream>>>(W_dt, Wdtb, DI * RNK / 4);

    // 1. in_proj
    gemm_bt<1><<<dim3(TOK / 128, (2 * DI) / 128), 256, 0, stream>>>(
        xb, Winb, DM, 2 * DI, xm, sres, nullptr, nullptr);

    // 2. causal depthwise conv + silu
    conv_silu_kernel<<<(TOK * DI) / 256, 256, 0, stream>>>(xm, conv_w, conv_b, xc);

    // 3. x_dbl = xc @ W_x^T  (MFMA, K-split 8, then reduce + emit dltB bf16)
    gemm_xdbl<<<dim3(TOK / 128, KSPL), 256, 0, stream>>>(xc, Wxb, part);
    reduce_part<<<(TOK * XDS / 4) / 256, 256, 0, stream>>>(
        (const float4*)part, (float4*)xdblP, dltB);

    // 4. delta = softplus(dltB @ W_dt^T + b_dt)  — MFMA, K=64
    gemm_bt<2><<<dim3(TOK / 128, DI / 128), 256, 0, stream>>>(
        dltB, Wdtb, RNK, DI, nullptr, nullptr, delta, b_dt);

    // 5. chunked selective scan
    scan_pass1<<<dim3(DI / 256, B_SZ * NC), 256, 0, stream>>>(
        delta, xdblP, xc, A_log, hfin, aprod);
    scan_combine<<<(B_SZ * DI * NST) / 256, 256, 0, stream>>>(hfin, aprod, h0buf);
    scan_pass2<<<dim3(DI / 256, B_SZ * NC), 256, 0, stream>>>(
        delta, xdblP, xc, sres, A_log, D_par, h0buf, yfin);

    // 6. out = yfin @ W_out^T (f32 store)
    gemm_bt<0><<<dim3(TOK / 128, DM / 128), 256, 0, stream>>>(
        yfin, Woutb, DI, DM, nullptr, nullptr, out, nullptr);
}

// Round 7
// 353.025 us; speedup vs baseline: 1.2834x; 1.0619x over previous
//
#include <hip/hip_runtime.h>

typedef unsigned short u16;
typedef __attribute__((ext_vector_type(8))) short bf16x8;
typedef __attribute__((ext_vector_type(4))) float f32x4;

#define B_SZ   2
#define L_SZ   2048
#define DM     1024
#define DI     2048
#define NST    16
#define RNK    64
#define TOK    (B_SZ * L_SZ)   // 4096
#define NC     64              // scan chunks (R7: 32->64 for occupancy)
#define CLEN   (L_SZ / NC)     // 32 steps per chunk
#define XDS    128             // x_dbl row stride (padded from 96)
#define KSPL   8               // K-split for xdbl gemm

__device__ __forceinline__ float bf2f(u16 u) {
    return __uint_as_float(((unsigned int)u) << 16);
}
__device__ __forceinline__ u16 f2bf(float f) {
    unsigned int x = __float_as_uint(f);
    x += 0x7fffu + ((x >> 16) & 1u);   // RNE
    return (u16)(x >> 16);
}
__device__ __forceinline__ void bf2x2(unsigned int p, float& lo, float& hi) {
    lo = __uint_as_float(p << 16);
    hi = __uint_as_float(p & 0xffff0000u);
}
__device__ __forceinline__ float silu(float v) {
    return v / (1.f + __expf(-v));
}
__device__ __forceinline__ float softplus_f(float v) {
    return (v > 20.f) ? v : log1pf(__expf(v));
}
// 16-byte async global->LDS (gfx950). LDS dest = wave-uniform base + lane*16.
__device__ __forceinline__ void gload16(const u16* g, u16* l) {
    __builtin_amdgcn_global_load_lds(
        (const __attribute__((address_space(1))) void*)g,
        (__attribute__((address_space(3))) void*)l, 16, 0, 0);
}

// ---------------------------------------------------------------------------
// f32 -> bf16 conversion (vectorized x4); n4 = elements/4
// ---------------------------------------------------------------------------
__global__ __launch_bounds__(256)
void cvt_f2b(const float* __restrict__ src, u16* __restrict__ dst, int n4)
{
    const int i = blockIdx.x * 256 + threadIdx.x;
    if (i < n4) {
        const float4 v = ((const float4*)src)[i];
        ushort4 o;
        o.x = f2bf(v.x); o.y = f2bf(v.y); o.z = f2bf(v.z); o.w = f2bf(v.w);
        ((ushort4*)dst)[i] = o;
    }
}

// W_x [96 x 2048] f32 -> [128 x 2048] bf16, rows 96..127 zeroed
__global__ __launch_bounds__(256)
void cvt_wx(const float* __restrict__ src, u16* __restrict__ dst)
{
    const int i = blockIdx.x * 256 + threadIdx.x;   // [0, 128*2048/4)
    const int row = (i * 4) >> 11;
    ushort4 o;
    if (row < 96) {
        const float4 v = ((const float4*)src)[i];
        o.x = f2bf(v.x); o.y = f2bf(v.y); o.z = f2bf(v.z); o.w = f2bf(v.w);
    } else {
        o.x = o.y = o.z = o.w = 0;
    }
    ((ushort4*)dst)[i] = o;
}

// ---------------------------------------------------------------------------
// GEMM  C[M][N] = A[M][K] @ B[N][K]^T  (swapped-MFMA epilogue, gload16 staging)
// EPI==0: float4 store to outF ; EPI==1: in_proj split ; EPI==2: softplus+bias
// ---------------------------------------------------------------------------
template<int EPI>
__global__ __launch_bounds__(256, 2)
void gemm_bt(const u16* __restrict__ A, const u16* __restrict__ B,
             const int K, const int N,
             u16* __restrict__ out0, u16* __restrict__ out1,
             float* __restrict__ outF, const float* __restrict__ bias)
{
    __shared__ u16 sA[128 * 32];
    __shared__ u16 sB[128 * 32];

    const int tid  = threadIdx.x;
    const int rowBase = blockIdx.x << 7;
    const int colBase = blockIdx.y << 7;
    const int wave = tid >> 6, lane = tid & 63;
    const int wm = (wave >> 1) << 6;
    const int wn = (wave & 1) << 6;
    const int lrow = lane & 15, quad = lane >> 4;

    const int sr  = tid >> 2;
    const int skc = tid & 3;
    const u16* Ap = A + (size_t)(rowBase + sr) * K + skc * 8;
    const u16* Bp = B + (size_t)(colBase + sr) * K + skc * 8;
    const size_t rowJump = (size_t)64 * K;
    u16* lA0 = &sA[tid * 8];
    u16* lA1 = &sA[64 * 32 + tid * 8];
    u16* lB0 = &sB[tid * 8];
    u16* lB1 = &sB[64 * 32 + tid * 8];

    f32x4 acc[4][4];
#pragma unroll
    for (int i = 0; i < 4; ++i)
#pragma unroll
        for (int j = 0; j < 4; ++j) acc[i][j] = (f32x4){0.f, 0.f, 0.f, 0.f};

    const int KT = K >> 5;
    for (int kt = 0; kt < KT; ++kt) {
        const int ko = kt * 32;
        gload16(Ap + ko, lA0);
        gload16(Ap + ko + rowJump, lA1);
        gload16(Bp + ko, lB0);
        gload16(Bp + ko + rowJump, lB1);
        __syncthreads();

        bf16x8 af[4], bfr[4];
#pragma unroll
        for (int i = 0; i < 4; ++i)
            af[i] = *(const bf16x8*)&sA[(wm + i * 16 + lrow) * 32 + quad * 8];
#pragma unroll
        for (int j = 0; j < 4; ++j)
            bfr[j] = *(const bf16x8*)&sB[(wn + j * 16 + lrow) * 32 + quad * 8];

#pragma unroll
        for (int i = 0; i < 4; ++i)
#pragma unroll
            for (int j = 0; j < 4; ++j)
                acc[i][j] = __builtin_amdgcn_mfma_f32_16x16x32_bf16(
                    bfr[j], af[i], acc[i][j], 0, 0, 0);   // swapped: C^T frags
        __syncthreads();
    }

#pragma unroll
    for (int i = 0; i < 4; ++i) {
        const int token = rowBase + wm + i * 16 + lrow;
#pragma unroll
        for (int j = 0; j < 4; ++j) {
            const int ch = colBase + wn + j * 16 + quad * 4;
            const f32x4 v = acc[i][j];
            if (EPI == 0) {
                *(float4*)&outF[(size_t)token * N + ch] =
                    (float4){v[0], v[1], v[2], v[3]};
            } else if (EPI == 2) {
                const float4 bb = *(const float4*)&bias[ch];
                *(float4*)&outF[(size_t)token * N + ch] =
                    (float4){softplus_f(v[0] + bb.x), softplus_f(v[1] + bb.y),
                             softplus_f(v[2] + bb.z), softplus_f(v[3] + bb.w)};
            } else {
                if (ch < DI) {
                    ushort4 o;
                    o.x = f2bf(v[0]); o.y = f2bf(v[1]);
                    o.z = f2bf(v[2]); o.w = f2bf(v[3]);
                    *(ushort4*)&out0[(size_t)token * DI + ch] = o;
                } else {
                    ushort4 o;
                    o.x = f2bf(silu(v[0])); o.y = f2bf(silu(v[1]));
                    o.z = f2bf(silu(v[2])); o.w = f2bf(silu(v[3]));
                    *(ushort4*)&out1[(size_t)token * DI + (ch - DI)] = o;
                }
            }
        }
    }
}

// ---------------------------------------------------------------------------
// xdbl GEMM: part[ks][128 tokens][128] = xc_tile @ WxP^T over K-slice ks*256.
// ---------------------------------------------------------------------------
__global__ __launch_bounds__(256, 2)
void gemm_xdbl(const u16* __restrict__ A, const u16* __restrict__ B,
               float* __restrict__ part)
{
    __shared__ u16 sA[128 * 32];
    __shared__ u16 sB[128 * 32];

    const int tid  = threadIdx.x;
    const int rowBase = blockIdx.x << 7;
    const int ks   = blockIdx.y;
    const int k0   = ks * (DI / KSPL);
    const int wave = tid >> 6, lane = tid & 63;
    const int wm = (wave >> 1) << 6;
    const int wn = (wave & 1) << 6;
    const int lrow = lane & 15, quad = lane >> 4;

    const int sr  = tid >> 2;
    const int skc = tid & 3;
    const u16* Ap = A + (size_t)(rowBase + sr) * DI + k0 + skc * 8;
    const u16* Bp = B + (size_t)sr * DI + k0 + skc * 8;
    const size_t rowJump = (size_t)64 * DI;
    u16* lA0 = &sA[tid * 8];
    u16* lA1 = &sA[64 * 32 + tid * 8];
    u16* lB0 = &sB[tid * 8];
    u16* lB1 = &sB[64 * 32 + tid * 8];

    f32x4 acc[4][4];
#pragma unroll
    for (int i = 0; i < 4; ++i)
#pragma unroll
        for (int j = 0; j < 4; ++j) acc[i][j] = (f32x4){0.f, 0.f, 0.f, 0.f};

    const int KT = (DI / KSPL) >> 5;            // 8
    for (int kt = 0; kt < KT; ++kt) {
        const int ko = kt * 32;
        gload16(Ap + ko, lA0);
        gload16(Ap + ko + rowJump, lA1);
        gload16(Bp + ko, lB0);
        gload16(Bp + ko + rowJump, lB1);
        __syncthreads();

        bf16x8 af[4], bfr[4];
#pragma unroll
        for (int i = 0; i < 4; ++i)
            af[i] = *(const bf16x8*)&sA[(wm + i * 16 + lrow) * 32 + quad * 8];
#pragma unroll
        for (int j = 0; j < 4; ++j)
            bfr[j] = *(const bf16x8*)&sB[(wn + j * 16 + lrow) * 32 + quad * 8];

#pragma unroll
        for (int i = 0; i < 4; ++i)
#pragma unroll
            for (int j = 0; j < 4; ++j)
                acc[i][j] = __builtin_amdgcn_mfma_f32_16x16x32_bf16(
                    bfr[j], af[i], acc[i][j], 0, 0, 0);
        __syncthreads();
    }

    float* base = part + (size_t)ks * TOK * XDS;
#pragma unroll
    for (int i = 0; i < 4; ++i) {
        const int token = rowBase + wm + i * 16 + lrow;
#pragma unroll
        for (int j = 0; j < 4; ++j) {
            const int ch = wn + j * 16 + quad * 4;
            const f32x4 v = acc[i][j];
            *(float4*)&base[(size_t)token * XDS + ch] =
                (float4){v[0], v[1], v[2], v[3]};
        }
    }
}

// sum the 8 K-slice partials -> xdblP [TOK x 128] f32; also emit dltB
__global__ __launch_bounds__(256)
void reduce_part(const float4* __restrict__ part, float4* __restrict__ xdbl,
                 u16* __restrict__ dltB)
{
    const int i = blockIdx.x * 256 + threadIdx.x;   // [0, TOK*XDS/4)
    const int n4 = TOK * XDS / 4;
    float4 s = part[i];
#pragma unroll
    for (int ks = 1; ks < KSPL; ++ks) {
        const float4 v = part[(size_t)ks * n4 + i];
        s.x += v.x; s.y += v.y; s.z += v.z; s.w += v.w;
    }
    xdbl[i] = s;
    const int col4 = (i & (XDS / 4 - 1)) * 4;
    if (col4 < RNK) {
        const int row = i >> 5;                      // XDS/4 = 32
        ushort4 o;
        o.x = f2bf(s.x); o.y = f2bf(s.y); o.z = f2bf(s.z); o.w = f2bf(s.w);
        *(ushort4*)(dltB + (size_t)row * RNK + col4) = o;
    }
}

// ---------------------------------------------------------------------------
// causal depthwise conv (K=4) + silu
// ---------------------------------------------------------------------------
__global__ __launch_bounds__(256)
void conv_silu_kernel(const u16* __restrict__ xm, const float* __restrict__ cw,
                      const float* __restrict__ cb, u16* __restrict__ xc)
{
    const int idx = blockIdx.x * 256 + threadIdx.x;
    const int ch = idx & (DI - 1);
    const int t  = idx >> 11;
    const int l  = t & (L_SZ - 1);

    const float4 wv = *(const float4*)(cw + ch * 4);

    float acc = cb[ch];
    if (l >= 3) acc += wv.x * bf2f(xm[(size_t)(t - 3) * DI + ch]);
    if (l >= 2) acc += wv.y * bf2f(xm[(size_t)(t - 2) * DI + ch]);
    if (l >= 1) acc += wv.z * bf2f(xm[(size_t)(t - 1) * DI + ch]);
    acc += wv.w * bf2f(xm[(size_t)t * DI + ch]);

    xc[idx] = f2bf(silu(acc));
}

// ---------------------------------------------------------------------------
// Chunked selective scan (NC=64, CLEN=32). thread = channel; states in regs.
// pass1: local h (h0=0) + S = sum(delta). aprod reconstructed in combine as
// exp(A*S) (exact: prod exp(d_i*A) = exp(A*sum d_i)). Explicit next-step
// prefetch of d/x (latency-bound kernel, 16 waves/CU now).
// ---------------------------------------------------------------------------
__global__ __launch_bounds__(256)
void scan_pass1(const float* __restrict__ delta, const float* __restrict__ xdbl,
                const u16* __restrict__ xc, const float* __restrict__ A_log,
                float* __restrict__ hfin, float* __restrict__ Ssum)
{
    const int tid = threadIdx.x;
    const int ch  = blockIdx.x * 256 + tid;
    const int b   = blockIdx.y / NC;
    const int c   = blockIdx.y % NC;
    const int t0  = b * L_SZ + c * CLEN;

    __shared__ float sB[CLEN][16];
#pragma unroll
    for (int r = 0; r < (CLEN * 16) / 256; ++r) {
        const int idx = r * 256 + tid;
        const int i = idx >> 4, nn = idx & 15;
        sB[i][nn] = xdbl[(size_t)(t0 + i) * XDS + 64 + nn];
    }

    float A[16];
    {
        const float4* Ar = (const float4*)(A_log + (size_t)ch * 16);
#pragma unroll
        for (int k = 0; k < 4; ++k) {
            const float4 v = Ar[k];
            A[4*k+0] = -__expf(v.x); A[4*k+1] = -__expf(v.y);
            A[4*k+2] = -__expf(v.z); A[4*k+3] = -__expf(v.w);
        }
    }
    __syncthreads();

    float h[16];
#pragma unroll
    for (int n = 0; n < 16; ++n) h[n] = 0.f;
    float S = 0.f;

    float d  = delta[(size_t)t0 * DI + ch];
    float xv = bf2f(xc[(size_t)t0 * DI + ch]);

    for (int i = 0; i < CLEN; ++i) {
        float dn = 0.f, xn = 0.f;
        if (i + 1 < CLEN) {
            const size_t tn = (size_t)(t0 + i + 1);
            dn = delta[tn * DI + ch];
            xn = bf2f(xc[tn * DI + ch]);
        }
        const float dx = d * xv;
        S += d;
#pragma unroll
        for (int k = 0; k < 4; ++k) {
            const float4 Bv = *(const float4*)&sB[i][k * 4];
#pragma unroll
            for (int j = 0; j < 4; ++j) {
                const int n = k * 4 + j;
                const float e = __expf(d * A[n]);
                h[n] = e * h[n] + dx * (&Bv.x)[j];
            }
        }
        d = dn; xv = xn;
    }

    float* hp = hfin + ((size_t)(b * NC + c) * DI + ch) * 16;
#pragma unroll
    for (int k = 0; k < 4; ++k)
        *(float4*)(hp + 4 * k) = (float4){h[4*k], h[4*k+1], h[4*k+2], h[4*k+3]};
    Ssum[(size_t)(b * NC + c) * DI + ch] = S;
}

// combine: h0[c] = hfin[c-1] + exp(A*S[c-1])*h0[c-1]. thread=(b,ch,n)
__global__ __launch_bounds__(256)
void scan_combine(const float* __restrict__ hfin, const float* __restrict__ Ssum,
                  const float* __restrict__ A_log, float* __restrict__ h0buf)
{
    const int idx  = blockIdx.x * 256 + threadIdx.x;   // [0, B*DI*16)
    const int b    = idx >> 15;                         // DI*16 = 32768
    const int base = idx & 32767;                       // ch*16 + n
    const int ch   = base >> 4;
    const float A  = -__expf(A_log[base]);
    float h0 = 0.f;
#pragma unroll 4
    for (int c = 0; c < NC; ++c) {
        const size_t o = (size_t)(b * NC + c) * 32768 + base;
        h0buf[o] = h0;
        const float S = Ssum[(size_t)(b * NC + c) * DI + ch];
        h0 = hfin[o] + __expf(A * S) * h0;
    }
}

__global__ __launch_bounds__(256)
void scan_pass2(const float* __restrict__ delta, const float* __restrict__ xdbl,
                const u16* __restrict__ xc, const u16* __restrict__ sres,
                const float* __restrict__ A_log, const float* __restrict__ Dp,
                const float* __restrict__ h0buf, u16* __restrict__ yfin)
{
    const int tid = threadIdx.x;
    const int ch  = blockIdx.x * 256 + tid;
    const int b   = blockIdx.y / NC;
    const int c   = blockIdx.y % NC;
    const int t0  = b * L_SZ + c * CLEN;

    __shared__ float sB[CLEN][16], sC[CLEN][16];
#pragma unroll
    for (int r = 0; r < (CLEN * 16) / 256; ++r) {
        const int idx = r * 256 + tid;
        const int i = idx >> 4, nn = idx & 15;
        sB[i][nn] = xdbl[(size_t)(t0 + i) * XDS + 64 + nn];
        sC[i][nn] = xdbl[(size_t)(t0 + i) * XDS + 80 + nn];
    }

    float A[16];
    {
        const float4* Ar = (const float4*)(A_log + (size_t)ch * 16);
#pragma unroll
        for (int k = 0; k < 4; ++k) {
            const float4 v = Ar[k];
            A[4*k+0] = -__expf(v.x); A[4*k+1] = -__expf(v.y);
            A[4*k+2] = -__expf(v.z); A[4*k+3] = -__expf(v.w);
        }
    }
    const float Dval = Dp[ch];

    float h[16];
    {
        const float4* hp = (const float4*)(h0buf + (size_t)(b * NC + c) * 32768 + (size_t)ch * 16);
#pragma unroll
        for (int k = 0; k < 4; ++k) {
            const float4 v = hp[k];
            h[4*k+0] = v.x; h[4*k+1] = v.y; h[4*k+2] = v.z; h[4*k+3] = v.w;
        }
    }
    __syncthreads();

    float d  = delta[(size_t)t0 * DI + ch];
    float xv = bf2f(xc[(size_t)t0 * DI + ch]);
    float rv = bf2f(sres[(size_t)t0 * DI + ch]);

    for (int i = 0; i < CLEN; ++i) {
        float dn = 0.f, xn = 0.f, rn = 0.f;
        if (i + 1 < CLEN) {
            const size_t tn = (size_t)(t0 + i + 1);
            dn = delta[tn * DI + ch];
            xn = bf2f(xc[tn * DI + ch]);
            rn = bf2f(sres[tn * DI + ch]);
        }
        const float dx = d * xv;
        float acc0 = 0.f, acc1 = 0.f, acc2 = 0.f, acc3 = 0.f;
#pragma unroll
        for (int k = 0; k < 4; ++k) {
            const float4 Bv = *(const float4*)&sB[i][k * 4];
            const float4 Cv = *(const float4*)&sC[i][k * 4];
#pragma unroll
            for (int j = 0; j < 4; ++j) {
                const int n = k * 4 + j;
                const float e = __expf(d * A[n]);
                h[n] = e * h[n] + dx * (&Bv.x)[j];
                const float t = h[n] * (&Cv.x)[j];
                if (j == 0) acc0 += t; else if (j == 1) acc1 += t;
                else if (j == 2) acc2 += t; else acc3 += t;
            }
        }
        const float p = (acc0 + acc1) + (acc2 + acc3);
        const float y = (p + Dval * xv) * rv;
        yfin[(size_t)(t0 + i) * DI + ch] = f2bf(y);
        d = dn; xv = xn; rv = rn;
    }
}

// ---------------------------------------------------------------------------
extern "C" void kernel_launch(void* const* d_in, const int* in_sizes, int n_in,
                              void* d_out, int out_size, void* d_ws, size_t ws_size,
                              hipStream_t stream)
{
    const float* x      = (const float*)d_in[0];
    const float* W_in   = (const float*)d_in[1];
    const float* conv_w = (const float*)d_in[2];
    const float* conv_b = (const float*)d_in[3];
    const float* W_x    = (const float*)d_in[4];
    const float* W_dt   = (const float*)d_in[5];
    const float* b_dt   = (const float*)d_in[6];
    const float* A_log  = (const float*)d_in[7];
    const float* D_par  = (const float*)d_in[8];
    const float* W_out  = (const float*)d_in[9];
    float* out = (float*)d_out;

    char* ws = (char*)d_ws;
    size_t off = 0;
    u16* xb    = (u16*)(ws + off); off += (size_t)TOK * DM * 2;        //  8.4 MB
    u16* Winb  = (u16*)(ws + off); off += (size_t)(2 * DI) * DM * 2;   //  8.4 MB
    u16* Woutb = (u16*)(ws + off); off += (size_t)DM * DI * 2;         //  4.2 MB
    u16* Wxb   = (u16*)(ws + off); off += (size_t)XDS * DI * 2;        //  0.5 MB
    u16* Wdtb  = (u16*)(ws + off); off += (size_t)DI * RNK * 2;        //  0.3 MB
    u16* dltB  = (u16*)(ws + off); off += (size_t)TOK * RNK * 2;       //  0.5 MB
    u16* xm    = (u16*)(ws + off); off += (size_t)TOK * DI * 2;        // 16.8 MB
    u16* xc    = (u16*)(ws + off); off += (size_t)TOK * DI * 2;        // 16.8 MB
    u16* sres  = (u16*)(ws + off); off += (size_t)TOK * DI * 2;        // 16.8 MB
    float* xdblP = (float*)(ws + off); off += (size_t)TOK * XDS * 4;   //  2.1 MB
    float* delta = (float*)(ws + off); off += (size_t)TOK * DI * 4;    // 33.6 MB
    float* hfin  = (float*)(ws + off); off += (size_t)NC * B_SZ * DI * NST * 4; // 16.8 MB
    float* h0buf = (float*)(ws + off); off += (size_t)NC * B_SZ * DI * NST * 4; // 16.8 MB
    float* Ssum  = (float*)(ws + off); off += (size_t)NC * B_SZ * DI * 4;       //  1.0 MB
    u16* yfin = xm;              // xm dead after conv — reuse
    float* part = hfin;          // hfin (16.8 MB) dead until scan_pass1 — reuse

    // 0. convert GEMM operands f32 -> bf16
    cvt_f2b<<<(TOK * DM / 4 + 255) / 256, 256, 0, stream>>>(x, xb, TOK * DM / 4);
    cvt_f2b<<<(2 * DI * DM / 4 + 255) / 256, 256, 0, stream>>>(W_in, Winb, 2 * DI * DM / 4);
    cvt_f2b<<<(DM * DI / 4 + 255) / 256, 256, 0, stream>>>(W_out, Woutb, DM * DI / 4);
    cvt_wx<<<(XDS * DI / 4) / 256, 256, 0, stream>>>(W_x, Wxb);
    cvt_f2b<<<(DI * RNK / 4 + 255) / 256, 256, 0, stream>>>(W_dt, Wdtb, DI * RNK / 4);

    // 1. in_proj
    gemm_bt<1><<<dim3(TOK / 128, (2 * DI) / 128), 256, 0, stream>>>(
        xb, Winb, DM, 2 * DI, xm, sres, nullptr, nullptr);

    // 2. causal depthwise conv + silu
    conv_silu_kernel<<<(TOK * DI) / 256, 256, 0, stream>>>(xm, conv_w, conv_b, xc);

    // 3. x_dbl = xc @ W_x^T  (MFMA, K-split 8, then reduce + emit dltB bf16)
    gemm_xdbl<<<dim3(TOK / 128, KSPL), 256, 0, stream>>>(xc, Wxb, part);
    reduce_part<<<(TOK * XDS / 4) / 256, 256, 0, stream>>>(
        (const float4*)part, (float4*)xdblP, dltB);

    // 4. delta = softplus(dltB @ W_dt^T + b_dt)  — MFMA, K=64
    gemm_bt<2><<<dim3(TOK / 128, DI / 128), 256, 0, stream>>>(
        dltB, Wdtb, RNK, DI, nullptr, nullptr, delta, b_dt);

    // 5. chunked selective scan (NC=64)
    scan_pass1<<<dim3(DI / 256, B_SZ * NC), 256, 0, stream>>>(
        delta, xdblP, xc, A_log, hfin, Ssum);
    scan_combine<<<(B_SZ * DI * NST) / 256, 256, 0, stream>>>(
        hfin, Ssum, A_log, h0buf);
    scan_pass2<<<dim3(DI / 256, B_SZ * NC), 256, 0, stream>>>(
        delta, xdblP, xc, sres, A_log, D_par, h0buf, yfin);

    // 6. out = yfin @ W_out^T (f32 store)
    gemm_bt<0><<<dim3(TOK / 128, DM / 128), 256, 0, stream>>>(
        yfin, Woutb, DI, DM, nullptr, nullptr, out, nullptr);
}

// Round 8
// 342.353 us; speedup vs baseline: 1.3234x; 1.0312x over previous
//
#include <hip/hip_runtime.h>

typedef unsigned short u16;
typedef __attribute__((ext_vector_type(8))) short bf16x8;
typedef __attribute__((ext_vector_type(4))) float f32x4;

#define B_SZ   2
#define L_SZ   2048
#define DM     1024
#define DI     2048
#define NST    16
#define RNK    64
#define TOK    (B_SZ * L_SZ)   // 4096
#define NC     128             // scan chunks (R8: 64->128, 8 blocks/CU)
#define CLEN   (L_SZ / NC)     // 16 steps per chunk
#define XDS    128             // x_dbl row stride (padded from 96)
#define KSPL   8               // K-split for xdbl gemm

__device__ __forceinline__ float bf2f(u16 u) {
    return __uint_as_float(((unsigned int)u) << 16);
}
__device__ __forceinline__ u16 f2bf(float f) {
    unsigned int x = __float_as_uint(f);
    x += 0x7fffu + ((x >> 16) & 1u);   // RNE
    return (u16)(x >> 16);
}
__device__ __forceinline__ float silu(float v) {
    return v / (1.f + __expf(-v));
}
__device__ __forceinline__ float softplus_f(float v) {
    return (v > 20.f) ? v : log1pf(__expf(v));
}
// 16-byte async global->LDS (gfx950). LDS dest = wave-uniform base + lane*16.
__device__ __forceinline__ void gload16(const u16* g, u16* l) {
    __builtin_amdgcn_global_load_lds(
        (const __attribute__((address_space(1))) void*)g,
        (__attribute__((address_space(3))) void*)l, 16, 0, 0);
}
__device__ __forceinline__ ushort4 cvt4(const float4 v) {
    ushort4 o;
    o.x = f2bf(v.x); o.y = f2bf(v.y); o.z = f2bf(v.z); o.w = f2bf(v.w);
    return o;
}

// ---------------------------------------------------------------------------
// Fused f32 -> bf16 conversion of all 5 GEMM operands (one launch).
// Region boundaries in float4-quads.
// ---------------------------------------------------------------------------
#define Q_XB   1048576                    // TOK*DM/4
#define Q_WIN  (Q_XB + 1048576)           // + 2*DI*DM/4
#define Q_WOUT (Q_WIN + 524288)           // + DM*DI/4
#define Q_WX   (Q_WOUT + 65536)           // + XDS*DI/4 (padded)
#define Q_WDT  (Q_WX + 32768)             // + DI*RNK/4
__global__ __launch_bounds__(256)
void cvt_all(const float4* __restrict__ x,  const float4* __restrict__ Wi,
             const float4* __restrict__ Wo, const float4* __restrict__ Wx,
             const float4* __restrict__ Wd,
             ushort4* __restrict__ xb,  ushort4* __restrict__ Wib,
             ushort4* __restrict__ Wob, ushort4* __restrict__ Wxb,
             ushort4* __restrict__ Wdb)
{
    const int i = blockIdx.x * 256 + threadIdx.x;
    if (i < Q_XB) {
        xb[i] = cvt4(x[i]);
    } else if (i < Q_WIN) {
        const int j = i - Q_XB;  Wib[j] = cvt4(Wi[j]);
    } else if (i < Q_WOUT) {
        const int j = i - Q_WIN; Wob[j] = cvt4(Wo[j]);
    } else if (i < Q_WX) {
        const int j = i - Q_WOUT;
        const int row = (j * 4) >> 11;           // 2048 elems per row
        if (row < 96) Wxb[j] = cvt4(Wx[j]);
        else          Wxb[j] = (ushort4){0, 0, 0, 0};
    } else if (i < Q_WDT) {
        const int j = i - Q_WX;  Wdb[j] = cvt4(Wd[j]);
    }
}

// ---------------------------------------------------------------------------
// GEMM  C[M][N] = A[M][K] @ B[N][K]^T  (swapped-MFMA epilogue, gload16 staging)
// EPI==0: float4 store to outF ; EPI==1: in_proj split ; EPI==2: softplus+bias -> bf16
// ---------------------------------------------------------------------------
template<int EPI>
__global__ __launch_bounds__(256, 2)
void gemm_bt(const u16* __restrict__ A, const u16* __restrict__ B,
             const int K, const int N,
             u16* __restrict__ out0, u16* __restrict__ out1,
             float* __restrict__ outF, const float* __restrict__ bias)
{
    __shared__ u16 sA[128 * 32];
    __shared__ u16 sB[128 * 32];

    const int tid  = threadIdx.x;
    const int rowBase = blockIdx.x << 7;
    const int colBase = blockIdx.y << 7;
    const int wave = tid >> 6, lane = tid & 63;
    const int wm = (wave >> 1) << 6;
    const int wn = (wave & 1) << 6;
    const int lrow = lane & 15, quad = lane >> 4;

    const int sr  = tid >> 2;
    const int skc = tid & 3;
    const u16* Ap = A + (size_t)(rowBase + sr) * K + skc * 8;
    const u16* Bp = B + (size_t)(colBase + sr) * K + skc * 8;
    const size_t rowJump = (size_t)64 * K;
    u16* lA0 = &sA[tid * 8];
    u16* lA1 = &sA[64 * 32 + tid * 8];
    u16* lB0 = &sB[tid * 8];
    u16* lB1 = &sB[64 * 32 + tid * 8];

    f32x4 acc[4][4];
#pragma unroll
    for (int i = 0; i < 4; ++i)
#pragma unroll
        for (int j = 0; j < 4; ++j) acc[i][j] = (f32x4){0.f, 0.f, 0.f, 0.f};

    const int KT = K >> 5;
    for (int kt = 0; kt < KT; ++kt) {
        const int ko = kt * 32;
        gload16(Ap + ko, lA0);
        gload16(Ap + ko + rowJump, lA1);
        gload16(Bp + ko, lB0);
        gload16(Bp + ko + rowJump, lB1);
        __syncthreads();

        bf16x8 af[4], bfr[4];
#pragma unroll
        for (int i = 0; i < 4; ++i)
            af[i] = *(const bf16x8*)&sA[(wm + i * 16 + lrow) * 32 + quad * 8];
#pragma unroll
        for (int j = 0; j < 4; ++j)
            bfr[j] = *(const bf16x8*)&sB[(wn + j * 16 + lrow) * 32 + quad * 8];

#pragma unroll
        for (int i = 0; i < 4; ++i)
#pragma unroll
            for (int j = 0; j < 4; ++j)
                acc[i][j] = __builtin_amdgcn_mfma_f32_16x16x32_bf16(
                    bfr[j], af[i], acc[i][j], 0, 0, 0);   // swapped: C^T frags
        __syncthreads();
    }

#pragma unroll
    for (int i = 0; i < 4; ++i) {
        const int token = rowBase + wm + i * 16 + lrow;
#pragma unroll
        for (int j = 0; j < 4; ++j) {
            const int ch = colBase + wn + j * 16 + quad * 4;
            const f32x4 v = acc[i][j];
            if (EPI == 0) {
                *(float4*)&outF[(size_t)token * N + ch] =
                    (float4){v[0], v[1], v[2], v[3]};
            } else if (EPI == 2) {
                const float4 bb = *(const float4*)&bias[ch];
                ushort4 o;
                o.x = f2bf(softplus_f(v[0] + bb.x));
                o.y = f2bf(softplus_f(v[1] + bb.y));
                o.z = f2bf(softplus_f(v[2] + bb.z));
                o.w = f2bf(softplus_f(v[3] + bb.w));
                *(ushort4*)&out0[(size_t)token * N + ch] = o;
            } else {
                if (ch < DI) {
                    ushort4 o;
                    o.x = f2bf(v[0]); o.y = f2bf(v[1]);
                    o.z = f2bf(v[2]); o.w = f2bf(v[3]);
                    *(ushort4*)&out0[(size_t)token * DI + ch] = o;
                } else {
                    ushort4 o;
                    o.x = f2bf(silu(v[0])); o.y = f2bf(silu(v[1]));
                    o.z = f2bf(silu(v[2])); o.w = f2bf(silu(v[3]));
                    *(ushort4*)&out1[(size_t)token * DI + (ch - DI)] = o;
                }
            }
        }
    }
}

// ---------------------------------------------------------------------------
// xdbl GEMM: part[ks][128 tokens][128] = xc_tile @ WxP^T over K-slice ks*256.
// ---------------------------------------------------------------------------
__global__ __launch_bounds__(256, 2)
void gemm_xdbl(const u16* __restrict__ A, const u16* __restrict__ B,
               float* __restrict__ part)
{
    __shared__ u16 sA[128 * 32];
    __shared__ u16 sB[128 * 32];

    const int tid  = threadIdx.x;
    const int rowBase = blockIdx.x << 7;
    const int ks   = blockIdx.y;
    const int k0   = ks * (DI / KSPL);
    const int wave = tid >> 6, lane = tid & 63;
    const int wm = (wave >> 1) << 6;
    const int wn = (wave & 1) << 6;
    const int lrow = lane & 15, quad = lane >> 4;

    const int sr  = tid >> 2;
    const int skc = tid & 3;
    const u16* Ap = A + (size_t)(rowBase + sr) * DI + k0 + skc * 8;
    const u16* Bp = B + (size_t)sr * DI + k0 + skc * 8;
    const size_t rowJump = (size_t)64 * DI;
    u16* lA0 = &sA[tid * 8];
    u16* lA1 = &sA[64 * 32 + tid * 8];
    u16* lB0 = &sB[tid * 8];
    u16* lB1 = &sB[64 * 32 + tid * 8];

    f32x4 acc[4][4];
#pragma unroll
    for (int i = 0; i < 4; ++i)
#pragma unroll
        for (int j = 0; j < 4; ++j) acc[i][j] = (f32x4){0.f, 0.f, 0.f, 0.f};

    const int KT = (DI / KSPL) >> 5;            // 8
    for (int kt = 0; kt < KT; ++kt) {
        const int ko = kt * 32;
        gload16(Ap + ko, lA0);
        gload16(Ap + ko + rowJump, lA1);
        gload16(Bp + ko, lB0);
        gload16(Bp + ko + rowJump, lB1);
        __syncthreads();

        bf16x8 af[4], bfr[4];
#pragma unroll
        for (int i = 0; i < 4; ++i)
            af[i] = *(const bf16x8*)&sA[(wm + i * 16 + lrow) * 32 + quad * 8];
#pragma unroll
        for (int j = 0; j < 4; ++j)
            bfr[j] = *(const bf16x8*)&sB[(wn + j * 16 + lrow) * 32 + quad * 8];

#pragma unroll
        for (int i = 0; i < 4; ++i)
#pragma unroll
            for (int j = 0; j < 4; ++j)
                acc[i][j] = __builtin_amdgcn_mfma_f32_16x16x32_bf16(
                    bfr[j], af[i], acc[i][j], 0, 0, 0);
        __syncthreads();
    }

    float* base = part + (size_t)ks * TOK * XDS;
#pragma unroll
    for (int i = 0; i < 4; ++i) {
        const int token = rowBase + wm + i * 16 + lrow;
#pragma unroll
        for (int j = 0; j < 4; ++j) {
            const int ch = wn + j * 16 + quad * 4;
            const f32x4 v = acc[i][j];
            *(float4*)&base[(size_t)token * XDS + ch] =
                (float4){v[0], v[1], v[2], v[3]};
        }
    }
}

// sum the 8 K-slice partials -> xdblP [TOK x 128] f32; also emit dltB
__global__ __launch_bounds__(256)
void reduce_part(const float4* __restrict__ part, float4* __restrict__ xdbl,
                 u16* __restrict__ dltB)
{
    const int i = blockIdx.x * 256 + threadIdx.x;   // [0, TOK*XDS/4)
    const int n4 = TOK * XDS / 4;
    float4 s = part[i];
#pragma unroll
    for (int ks = 1; ks < KSPL; ++ks) {
        const float4 v = part[(size_t)ks * n4 + i];
        s.x += v.x; s.y += v.y; s.z += v.z; s.w += v.w;
    }
    xdbl[i] = s;
    const int col4 = (i & (XDS / 4 - 1)) * 4;
    if (col4 < RNK) {
        const int row = i >> 5;                      // XDS/4 = 32
        *(ushort4*)(dltB + (size_t)row * RNK + col4) = cvt4(s);
    }
}

// ---------------------------------------------------------------------------
// causal depthwise conv (K=4) + silu
// ---------------------------------------------------------------------------
__global__ __launch_bounds__(256)
void conv_silu_kernel(const u16* __restrict__ xm, const float* __restrict__ cw,
                      const float* __restrict__ cb, u16* __restrict__ xc)
{
    const int idx = blockIdx.x * 256 + threadIdx.x;
    const int ch = idx & (DI - 1);
    const int t  = idx >> 11;
    const int l  = t & (L_SZ - 1);

    const float4 wv = *(const float4*)(cw + ch * 4);

    float acc = cb[ch];
    if (l >= 3) acc += wv.x * bf2f(xm[(size_t)(t - 3) * DI + ch]);
    if (l >= 2) acc += wv.y * bf2f(xm[(size_t)(t - 2) * DI + ch]);
    if (l >= 1) acc += wv.z * bf2f(xm[(size_t)(t - 1) * DI + ch]);
    acc += wv.w * bf2f(xm[(size_t)t * DI + ch]);

    xc[idx] = f2bf(silu(acc));
}

// ---------------------------------------------------------------------------
// Chunked selective scan (NC=128, CLEN=16). thread = channel; states in regs.
// delta is bf16 now. Branchless clamped prefetch of next-step scalars.
// ---------------------------------------------------------------------------
__global__ __launch_bounds__(256)
void scan_pass1(const u16* __restrict__ delta, const float* __restrict__ xdbl,
                const u16* __restrict__ xc, const float* __restrict__ A_log,
                float* __restrict__ hfin, float* __restrict__ Ssum)
{
    const int tid = threadIdx.x;
    const int ch  = blockIdx.x * 256 + tid;
    const int b   = blockIdx.y / NC;
    const int c   = blockIdx.y % NC;
    const int t0  = b * L_SZ + c * CLEN;

    __shared__ float sB[CLEN][16];
    {   // CLEN*16 == 256
        const int i = tid >> 4, nn = tid & 15;
        sB[i][nn] = xdbl[(size_t)(t0 + i) * XDS + 64 + nn];
    }

    float A[16];
    {
        const float4* Ar = (const float4*)(A_log + (size_t)ch * 16);
#pragma unroll
        for (int k = 0; k < 4; ++k) {
            const float4 v = Ar[k];
            A[4*k+0] = -__expf(v.x); A[4*k+1] = -__expf(v.y);
            A[4*k+2] = -__expf(v.z); A[4*k+3] = -__expf(v.w);
        }
    }
    __syncthreads();

    float h[16];
#pragma unroll
    for (int n = 0; n < 16; ++n) h[n] = 0.f;
    float S = 0.f;

    float d  = bf2f(delta[(size_t)t0 * DI + ch]);
    float xv = bf2f(xc[(size_t)t0 * DI + ch]);

    for (int i = 0; i < CLEN; ++i) {
        const int in_ = (i + 1 < CLEN) ? (i + 1) : i;       // clamped prefetch
        const float dn = bf2f(delta[(size_t)(t0 + in_) * DI + ch]);
        const float xn = bf2f(xc[(size_t)(t0 + in_) * DI + ch]);
        const float dx = d * xv;
        S += d;
#pragma unroll
        for (int k = 0; k < 4; ++k) {
            const float4 Bv = *(const float4*)&sB[i][k * 4];
#pragma unroll
            for (int j = 0; j < 4; ++j) {
                const int n = k * 4 + j;
                const float e = __expf(d * A[n]);
                h[n] = e * h[n] + dx * (&Bv.x)[j];
            }
        }
        d = dn; xv = xn;
    }

    float* hp = hfin + ((size_t)(b * NC + c) * DI + ch) * 16;
#pragma unroll
    for (int k = 0; k < 4; ++k)
        *(float4*)(hp + 4 * k) = (float4){h[4*k], h[4*k+1], h[4*k+2], h[4*k+3]};
    Ssum[(size_t)(b * NC + c) * DI + ch] = S;
}

// combine: h0[c] = hfin[c-1] + exp(A*S[c-1])*h0[c-1]. thread=(b,ch,n).
// h0buf stored bf16 (handoff only; chain stays f32).
__global__ __launch_bounds__(256)
void scan_combine(const float* __restrict__ hfin, const float* __restrict__ Ssum,
                  const float* __restrict__ A_log, u16* __restrict__ h0buf)
{
    const int idx  = blockIdx.x * 256 + threadIdx.x;   // [0, B*DI*16)
    const int b    = idx >> 15;                         // DI*16 = 32768
    const int base = idx & 32767;                       // ch*16 + n
    const int ch   = base >> 4;
    const float A  = -__expf(A_log[base]);
    float h0 = 0.f;
#pragma unroll 4
    for (int c = 0; c < NC; ++c) {
        const size_t o = (size_t)(b * NC + c) * 32768 + base;
        h0buf[o] = f2bf(h0);
        const float S = Ssum[(size_t)(b * NC + c) * DI + ch];
        h0 = hfin[o] + __expf(A * S) * h0;
    }
}

__global__ __launch_bounds__(256)
void scan_pass2(const u16* __restrict__ delta, const float* __restrict__ xdbl,
                const u16* __restrict__ xc, const u16* __restrict__ sres,
                const float* __restrict__ A_log, const float* __restrict__ Dp,
                const u16* __restrict__ h0buf, u16* __restrict__ yfin)
{
    const int tid = threadIdx.x;
    const int ch  = blockIdx.x * 256 + tid;
    const int b   = blockIdx.y / NC;
    const int c   = blockIdx.y % NC;
    const int t0  = b * L_SZ + c * CLEN;

    __shared__ float sB[CLEN][16], sC[CLEN][16];
    {   // CLEN*16 == 256
        const int i = tid >> 4, nn = tid & 15;
        sB[i][nn] = xdbl[(size_t)(t0 + i) * XDS + 64 + nn];
        sC[i][nn] = xdbl[(size_t)(t0 + i) * XDS + 80 + nn];
    }

    float A[16];
    {
        const float4* Ar = (const float4*)(A_log + (size_t)ch * 16);
#pragma unroll
        for (int k = 0; k < 4; ++k) {
            const float4 v = Ar[k];
            A[4*k+0] = -__expf(v.x); A[4*k+1] = -__expf(v.y);
            A[4*k+2] = -__expf(v.z); A[4*k+3] = -__expf(v.w);
        }
    }
    const float Dval = Dp[ch];

    float h[16];
    {
        const u16* hp = h0buf + (size_t)(b * NC + c) * 32768 + (size_t)ch * 16;
#pragma unroll
        for (int k = 0; k < 4; ++k) {
            const ushort4 q = *(const ushort4*)(hp + 4 * k);
            h[4*k+0] = bf2f(q.x); h[4*k+1] = bf2f(q.y);
            h[4*k+2] = bf2f(q.z); h[4*k+3] = bf2f(q.w);
        }
    }
    __syncthreads();

    float d  = bf2f(delta[(size_t)t0 * DI + ch]);
    float xv = bf2f(xc[(size_t)t0 * DI + ch]);
    float rv = bf2f(sres[(size_t)t0 * DI + ch]);

    for (int i = 0; i < CLEN; ++i) {
        const int in_ = (i + 1 < CLEN) ? (i + 1) : i;       // clamped prefetch
        const float dn = bf2f(delta[(size_t)(t0 + in_) * DI + ch]);
        const float xn = bf2f(xc[(size_t)(t0 + in_) * DI + ch]);
        const float rn = bf2f(sres[(size_t)(t0 + in_) * DI + ch]);
        const float dx = d * xv;
        float acc0 = 0.f, acc1 = 0.f, acc2 = 0.f, acc3 = 0.f;
#pragma unroll
        for (int k = 0; k < 4; ++k) {
            const float4 Bv = *(const float4*)&sB[i][k * 4];
            const float4 Cv = *(const float4*)&sC[i][k * 4];
#pragma unroll
            for (int j = 0; j < 4; ++j) {
                const int n = k * 4 + j;
                const float e = __expf(d * A[n]);
                h[n] = e * h[n] + dx * (&Bv.x)[j];
                const float t = h[n] * (&Cv.x)[j];
                if (j == 0) acc0 += t; else if (j == 1) acc1 += t;
                else if (j == 2) acc2 += t; else acc3 += t;
            }
        }
        const float p = (acc0 + acc1) + (acc2 + acc3);
        const float y = (p + Dval * xv) * rv;
        yfin[(size_t)(t0 + i) * DI + ch] = f2bf(y);
        d = dn; xv = xn; rv = rn;
    }
}

// ---------------------------------------------------------------------------
extern "C" void kernel_launch(void* const* d_in, const int* in_sizes, int n_in,
                              void* d_out, int out_size, void* d_ws, size_t ws_size,
                              hipStream_t stream)
{
    const float* x      = (const float*)d_in[0];
    const float* W_in   = (const float*)d_in[1];
    const float* conv_w = (const float*)d_in[2];
    const float* conv_b = (const float*)d_in[3];
    const float* W_x    = (const float*)d_in[4];
    const float* W_dt   = (const float*)d_in[5];
    const float* b_dt   = (const float*)d_in[6];
    const float* A_log  = (const float*)d_in[7];
    const float* D_par  = (const float*)d_in[8];
    const float* W_out  = (const float*)d_in[9];
    float* out = (float*)d_out;

    char* ws = (char*)d_ws;
    size_t off = 0;
    u16* xb    = (u16*)(ws + off); off += (size_t)TOK * DM * 2;        //  8.4 MB
    u16* Winb  = (u16*)(ws + off); off += (size_t)(2 * DI) * DM * 2;   //  8.4 MB
    u16* Woutb = (u16*)(ws + off); off += (size_t)DM * DI * 2;         //  4.2 MB
    u16* Wxb   = (u16*)(ws + off); off += (size_t)XDS * DI * 2;        //  0.5 MB
    u16* Wdtb  = (u16*)(ws + off); off += (size_t)DI * RNK * 2;        //  0.3 MB
    u16* dltB  = (u16*)(ws + off); off += (size_t)TOK * RNK * 2;       //  0.5 MB
    u16* xm    = (u16*)(ws + off); off += (size_t)TOK * DI * 2;        // 16.8 MB
    u16* xc    = (u16*)(ws + off); off += (size_t)TOK * DI * 2;        // 16.8 MB
    u16* sres  = (u16*)(ws + off); off += (size_t)TOK * DI * 2;        // 16.8 MB
    float* xdblP = (float*)(ws + off); off += (size_t)TOK * XDS * 4;   //  2.1 MB
    u16* dlt16   = (u16*)(ws + off);   off += (size_t)TOK * DI * 2;    // 16.8 MB (bf16 delta)
    float* hfin  = (float*)(ws + off); off += (size_t)NC * B_SZ * DI * NST * 4; // 33.6 MB
    u16* h0buf   = (u16*)(ws + off);   off += (size_t)NC * B_SZ * DI * NST * 2; // 16.8 MB
    float* Ssum  = (float*)(ws + off); off += (size_t)NC * B_SZ * DI * 4;       //  2.1 MB
    u16* yfin = xm;              // xm dead after conv — reuse
    float* part = hfin;          // hfin (33.6 MB) dead until scan_pass1 — reuse (needs 16.8)

    // 0. convert all GEMM operands f32 -> bf16 (single launch)
    cvt_all<<<(Q_WDT + 255) / 256, 256, 0, stream>>>(
        (const float4*)x, (const float4*)W_in, (const float4*)W_out,
        (const float4*)W_x, (const float4*)W_dt,
        (ushort4*)xb, (ushort4*)Winb, (ushort4*)Woutb,
        (ushort4*)Wxb, (ushort4*)Wdtb);

    // 1. in_proj
    gemm_bt<1><<<dim3(TOK / 128, (2 * DI) / 128), 256, 0, stream>>>(
        xb, Winb, DM, 2 * DI, xm, sres, nullptr, nullptr);

    // 2. causal depthwise conv + silu
    conv_silu_kernel<<<(TOK * DI) / 256, 256, 0, stream>>>(xm, conv_w, conv_b, xc);

    // 3. x_dbl = xc @ W_x^T  (MFMA, K-split 8, then reduce + emit dltB bf16)
    gemm_xdbl<<<dim3(TOK / 128, KSPL), 256, 0, stream>>>(xc, Wxb, part);
    reduce_part<<<(TOK * XDS / 4) / 256, 256, 0, stream>>>(
        (const float4*)part, (float4*)xdblP, dltB);

    // 4. delta = softplus(dltB @ W_dt^T + b_dt)  — MFMA K=64, bf16 output
    gemm_bt<2><<<dim3(TOK / 128, DI / 128), 256, 0, stream>>>(
        dltB, Wdtb, RNK, DI, dlt16, nullptr, nullptr, b_dt);

    // 5. chunked selective scan (NC=128)
    scan_pass1<<<dim3(DI / 256, B_SZ * NC), 256, 0, stream>>>(
        dlt16, xdblP, xc, A_log, hfin, Ssum);
    scan_combine<<<(B_SZ * DI * NST) / 256, 256, 0, stream>>>(
        hfin, Ssum, A_log, h0buf);
    scan_pass2<<<dim3(DI / 256, B_SZ * NC), 256, 0, stream>>>(
        dlt16, xdblP, xc, sres, A_log, D_par, h0buf, yfin);

    // 6. out = yfin @ W_out^T (f32 store)
    gemm_bt<0><<<dim3(TOK / 128, DM / 128), 256, 0, stream>>>(
        yfin, Woutb, DI, DM, nullptr, nullptr, out, nullptr);
}